// Round 9
// baseline (267.669 us; speedup 1.0000x reference)
//
#include <hip/hip_runtime.h>

#define BN_EPS 1e-5f

// ws layout (floats)
#define OFF_PBN     0          // [256 blk][32]  conv BN partials (sum k<16, sq 16+k)
#define OFF_PSR     8192       // [512 blk][32]  SR/SRR partials
#define OFF_PSX     24576      // [512 blk][256] SX partials
#define OFF_PSXX    155648     // [512 blk][256] SXX partials
#define OFF_CROSSR  286720     // [4 sg][4 b][16 k][256 c]
#define OFF_FIN     352256     // [4 b][64]  (SR[16], SRR[16], SCALE[16], pad)
#define OFF_SXF     352512     // [4 b][2 h][2 {sx,sxx}][256 c] = 4096
#define OFF_CW      356608     // [b][k][4096] = 262144
#define OFF_PCX     618752     // [(b*128+s)][16][256] = 2097152
#define OFF_BAR     2715904    // 3 barrier counters (uint)

#define CONV_FMA(W, K0)                                  \
    acc[K0][0] = fmaf(W, xv.x, acc[K0][0]);              \
    acc[K0][1] = fmaf(W, xv.y, acc[K0][1]);              \
    acc[K0][2] = fmaf(W, xv.z, acc[K0][2]);              \
    acc[K0][3] = fmaf(W, xv.w, acc[K0][3]);

#define FMA16(v, rp)                                     \
    {                                                    \
        const float4* rq_ = (const float4*)(rp);         \
        float4 r0_ = rq_[0], r1_ = rq_[1];               \
        float4 r2_ = rq_[2], r3_ = rq_[3];               \
        acc[0]  = fmaf(v, r0_.x, acc[0]);                \
        acc[1]  = fmaf(v, r0_.y, acc[1]);                \
        acc[2]  = fmaf(v, r0_.z, acc[2]);                \
        acc[3]  = fmaf(v, r0_.w, acc[3]);                \
        acc[4]  = fmaf(v, r1_.x, acc[4]);                \
        acc[5]  = fmaf(v, r1_.y, acc[5]);                \
        acc[6]  = fmaf(v, r1_.z, acc[6]);                \
        acc[7]  = fmaf(v, r1_.w, acc[7]);                \
        acc[8]  = fmaf(v, r2_.x, acc[8]);                \
        acc[9]  = fmaf(v, r2_.y, acc[9]);                \
        acc[10] = fmaf(v, r2_.z, acc[10]);               \
        acc[11] = fmaf(v, r2_.w, acc[11]);               \
        acc[12] = fmaf(v, r3_.x, acc[12]);               \
        acc[13] = fmaf(v, r3_.y, acc[13]);               \
        acc[14] = fmaf(v, r3_.z, acc[14]);               \
        acc[15] = fmaf(v, r3_.w, acc[15]);               \
    }

// Grid barrier: all 512 blocks guaranteed co-resident (see capacity argument in
// the launcher). Counter zeroed by captured hipMemsetAsync each launch.
__device__ __forceinline__ void gbar(unsigned* cnt, unsigned target) {
    __syncthreads();
    if (threadIdx.x == 0) {
        __threadfence();
        __hip_atomic_fetch_add(cnt, 1u, __ATOMIC_ACQ_REL, __HIP_MEMORY_SCOPE_AGENT);
        while (__hip_atomic_load(cnt, __ATOMIC_ACQUIRE, __HIP_MEMORY_SCOPE_AGENT)
               < target)
            __builtin_amdgcn_s_sleep(2);
        __threadfence();
    }
    __syncthreads();
}

// Single kernel, 512 blocks x 256 threads, 49.8 KB LDS, all blocks co-resident.
__global__ __launch_bounds__(256, 2) void k_all(const float* __restrict__ x,
                                                const float* __restrict__ w,
                                                const float* __restrict__ gamma,
                                                const float* __restrict__ beta,
                                                float* __restrict__ ws,
                                                float* __restrict__ out) {
    // lds[0..8192) = xl (persists across barrier 1)
    // lds[8192..)  = phase A {wlT 4124, bnl 128} / phase B {rl 512, red1 256,
    //                red2 256, bnred 256} / phase C {srl 4096}
    __shared__ float lds[12448];
    unsigned* bar = (unsigned*)(/*ws base*/ nullptr);  // set below (avoid reorder)
    float* xl = lds;
    int bid = blockIdx.x;
    int t   = threadIdx.x;
    bar = (unsigned*)(ws + OFF_BAR);

    // ======= Pre-barrier: stage phase-B x slab into LDS (ALL 512 blocks) =======
    {
        int b = bid >> 7;
        int s = bid & 127;
        #pragma unroll
        for (int j = 0; j < 8; ++j) {
            int F  = j * 256 + t;            // 2048 float4s of the 256c x 32i slab
            int cc = F >> 3, i4 = F & 7;
            const float* pa = x + (size_t)(b * 256 + cc) * 4096 + s * 32 + i4 * 4;
            float4 v = *(const float4*)pa;
            int ib = i4 * 4;
            xl[(ib + 0) * 256 + (cc ^ (ib + 0))] = v.x;
            xl[(ib + 1) * 256 + (cc ^ (ib + 1))] = v.y;
            xl[(ib + 2) * 256 + (cc ^ (ib + 2))] = v.z;
            xl[(ib + 3) * 256 + (cc ^ (ib + 3))] = v.w;
        }
    }

    // ================= Phase A: conv + BN partials (blocks 0-255) =================
    if (bid < 256) {
        float* wlT = lds + 8192;             // wlT[c*16 + (c>>5)*4 + k]
        float* bnl = lds + 8192 + 4124;      // [4][32]
        int b   = bid >> 6;
        int ich = bid & 63;
        int cp  = t & 15;
        int il  = t >> 4;
        int wv  = t >> 6;

        for (int m = t; m < 4096; m += 256) {
            int k = m >> 8, c = m & 255;
            wlT[(c << 4) + ((c >> 5) << 2) + k] = w[m];
        }
        __syncthreads();

        float acc[16][4];
        #pragma unroll
        for (int k = 0; k < 16; ++k) {
            #pragma unroll
            for (int e = 0; e < 4; ++e) acc[k][e] = 0.f;
        }

        const float* xp = x + (size_t)(b * 256 + cp * 16) * 4096 + ich * 64 + il * 4;
        #pragma unroll
        for (int cc = 0; cc < 16; ++cc) {
            float4 xv = *(const float4*)(xp + (size_t)cc * 4096);
            int c = cp * 16 + cc;
            const float4* wr = (const float4*)&wlT[(c << 4) + ((c >> 5) << 2)];
            float4 w0 = wr[0], w1 = wr[1], w2 = wr[2], w3 = wr[3];
            CONV_FMA(w0.x, 0)  CONV_FMA(w0.y, 1)  CONV_FMA(w0.z, 2)  CONV_FMA(w0.w, 3)
            CONV_FMA(w1.x, 4)  CONV_FMA(w1.y, 5)  CONV_FMA(w1.z, 6)  CONV_FMA(w1.w, 7)
            CONV_FMA(w2.x, 8)  CONV_FMA(w2.y, 9)  CONV_FMA(w2.z, 10) CONV_FMA(w2.w, 11)
            CONV_FMA(w3.x, 12) CONV_FMA(w3.y, 13) CONV_FMA(w3.z, 14) CONV_FMA(w3.w, 15)
        }

        // in-wave reduce-scatter over cp (lane bits 0-3); final k = bitrev4(cp)
        float r8[8][4];
        #pragma unroll
        for (int r = 0; r < 8; ++r) {
            #pragma unroll
            for (int e = 0; e < 4; ++e) {
                float lo = acc[r][e]     + __shfl_xor(acc[r][e], 1);
                float hi = acc[r + 8][e] + __shfl_xor(acc[r + 8][e], 1);
                r8[r][e] = (cp & 1) ? hi : lo;
            }
        }
        float r4v[4][4];
        #pragma unroll
        for (int r = 0; r < 4; ++r) {
            #pragma unroll
            for (int e = 0; e < 4; ++e) {
                float lo = r8[r][e]     + __shfl_xor(r8[r][e], 2);
                float hi = r8[r + 4][e] + __shfl_xor(r8[r + 4][e], 2);
                r4v[r][e] = (cp & 2) ? hi : lo;
            }
        }
        float r2[2][4];
        #pragma unroll
        for (int r = 0; r < 2; ++r) {
            #pragma unroll
            for (int e = 0; e < 4; ++e) {
                float lo = r4v[r][e]     + __shfl_xor(r4v[r][e], 4);
                float hi = r4v[r + 2][e] + __shfl_xor(r4v[r + 2][e], 4);
                r2[r][e] = (cp & 4) ? hi : lo;
            }
        }
        float r1[4];
        #pragma unroll
        for (int e = 0; e < 4; ++e) {
            float lo = r2[0][e] + __shfl_xor(r2[0][e], 8);
            float hi = r2[1][e] + __shfl_xor(r2[1][e], 8);
            r1[e] = (cp & 8) ? hi : lo;
        }
        int ko = ((cp & 1) << 3) | (((cp >> 1) & 1) << 2) | (((cp >> 2) & 1) << 1)
               | ((cp >> 3) & 1);

        float4 st;
        st.x = r1[0]; st.y = r1[1]; st.z = r1[2]; st.w = r1[3];
        *(float4*)(ws + OFF_CW + (size_t)b * 65536 + (size_t)ko * 4096
                   + ich * 64 + il * 4) = st;

        float s1 = r1[0] + r1[1] + r1[2] + r1[3];
        float s2 = r1[0]*r1[0] + r1[1]*r1[1] + r1[2]*r1[2] + r1[3]*r1[3];
        #pragma unroll
        for (int m = 16; m <= 32; m <<= 1) {
            s1 += __shfl_xor(s1, m);
            s2 += __shfl_xor(s2, m);
        }
        if ((t & 48) == 0) { bnl[wv * 32 + ko] = s1; bnl[wv * 32 + 16 + ko] = s2; }
        __syncthreads();
        if (t < 32) {
            ws[OFF_PBN + bid * 32 + t] = bnl[0 + t] + bnl[32 + t]
                                       + bnl[64 + t] + bnl[96 + t];
        }
    }
    gbar(bar + 0, 512);

    // ===== Phase B: BN apply + Cross/Sx/Sxx partials (all 512 blocks) =====
    {
        float* rl    = lds + 8192;       // 512
        float* red1  = lds + 8704;       // 256
        float* red2  = lds + 8960;       // 256
        float* bnred = lds + 9216;       // 256
        int b  = bid >> 7;
        int s  = bid & 127;
        int kp = s >> 3;                 // flat slab of 512 inside one orig channel
        float* pcx = ws + OFF_PCX;

        {   // BN stats: deterministic reduce of 256x32 partials
            int col = t & 31, row0 = t >> 5;
            float p = 0.f;
            for (int m = row0; m < 256; m += 8) p += ws[OFF_PBN + m * 32 + col];
            bnred[t] = p;
        }
        __syncthreads();
        float s1 = 0.f, s2 = 0.f;
        #pragma unroll
        for (int j = 0; j < 8; ++j) {
            s1 += bnred[j * 32 + kp];
            s2 += bnred[j * 32 + 16 + kp];
        }
        float mean = s1 * (1.f / 16384.f);
        float var  = s2 * (1.f / 16384.f) - mean * mean;
        float aa   = gamma[kp] * rsqrtf(var + BN_EPS);
        float bb   = beta[kp] - mean * aa;

        // r values: BN+ReLU of this slab's 512 flat cw entries; k2 = flat & 15
        const float* cwp = ws + OFF_CW + (size_t)b * 65536 + (size_t)kp * 4096
                         + (size_t)(s & 7) * 512;
        float sr = 0.f, srr = 0.f;
        #pragma unroll
        for (int j = 0; j < 2; ++j) {
            float v = cwp[t + j * 256];
            v = fmaxf(fmaf(v, aa, bb), 0.f);
            rl[t + j * 256] = v;
            sr += v; srr += v * v;
        }
        red1[t] = sr; red2[t] = srr;
        __syncthreads();

        if (t < 16) {
            float a1 = 0.f, a2 = 0.f;
            for (int m = t; m < 256; m += 16) { a1 += red1[m]; a2 += red2[m]; }
            ws[OFF_PSR + bid * 32 + t]      = a1;
            ws[OFF_PSR + bid * 32 + 16 + t] = a2;
        }

        // Cross partial: thread = channel c; 32 i from swizzled LDS; rl broadcast
        int c = t;
        float acc[16];
        #pragma unroll
        for (int k = 0; k < 16; ++k) acc[k] = 0.f;
        float xs = 0.f, xs2 = 0.f;
        #pragma unroll
        for (int ii = 0; ii < 32; ++ii) {
            float xv = xl[ii * 256 + (c ^ ii)];
            xs += xv; xs2 += xv * xv;
            FMA16(xv, rl + ii * 16);
        }

        ws[OFF_PSX  + bid * 256 + c] = xs;
        ws[OFF_PSXX + bid * 256 + c] = xs2;
        float* pp = pcx + (size_t)(bid * 16) * 256 + c;
        #pragma unroll
        for (int k = 0; k < 16; ++k) pp[(size_t)k * 256] = acc[k];
    }
    gbar(bar + 1, 512);

    // ===== Phase C: Cross reduce (0-255) || SR/SRR/SCALE (256-259) || Sx/Sxx (260-267)
    if (bid < 256) {
        int b  = bid >> 6;
        int k  = (bid >> 2) & 15;
        int sg = bid & 3;
        int c  = t;
        const float* pcx = ws + OFF_PCX;
        float acc = 0.f;
        #pragma unroll 8
        for (int m = 0; m < 32; ++m) {
            int sl = sg * 32 + m;
            acc += pcx[(size_t)((b * 128 + sl) * 16 + k) * 256 + c];
        }
        ws[OFF_CROSSR + ((sg * 4 + b) * 16 + k) * 256 + c] = acc;
    } else if (bid < 260) {
        int b = bid - 256;
        float* srl = lds;                // 4096 (xl dead)
        const float* psr = ws + OFF_PSR + (size_t)b * 128 * 32;
        #pragma unroll
        for (int j = 0; j < 16; ++j) srl[j * 256 + t] = psr[j * 256 + t];
        __syncthreads();
        if (t < 16) {
            float v = 0.f;
            for (int s = 0; s < 128; ++s) v += srl[s * 32 + t];
            ws[OFF_FIN + b * 64 + t] = v;                 // SR[k2]
        } else if (t < 32) {
            int k = t - 16;
            float v = 0.f;
            for (int s = 0; s < 128; ++s) v += srl[s * 32 + 16 + k];
            ws[OFF_FIN + b * 64 + 16 + k] = v;            // SRR[k2]
        } else if (t < 48) {
            int kp = t - 32;
            float v = 0.f;
            for (int s = kp * 8; s < kp * 8 + 8; ++s)
                for (int k2 = 0; k2 < 16; ++k2) v += srl[s * 32 + k2];
            ws[OFF_FIN + b * 64 + 32 + kp] = v;           // SCALE[kp] (pre /4096)
        }
    } else if (bid < 268) {
        int q = bid - 260;
        int b = q >> 1, h = q & 1;
        const float* psx  = ws + OFF_PSX  + (size_t)b * 128 * 256;
        const float* psxx = ws + OFF_PSXX + (size_t)b * 128 * 256;
        float sx = 0.f, sxx = 0.f;
        for (int p = h * 64; p < h * 64 + 64; ++p) {
            sx  += psx[p * 256 + t];
            sxx += psxx[p * 256 + t];
        }
        ws[OFF_SXF + ((b * 2 + h) * 2 + 0) * 256 + t] = sx;
        ws[OFF_SXF + ((b * 2 + h) * 2 + 1) * 256 + t] = sxx;
    }
    gbar(bar + 2, 512);

    // ================= Phase D: softmax + output (blocks 0-3) =================
    if (bid < 4) {
        int b = bid;
        int c = t;
        float sx  = ws[OFF_SXF + ((b * 2 + 0) * 2 + 0) * 256 + c]
                  + ws[OFF_SXF + ((b * 2 + 1) * 2 + 0) * 256 + c];
        float sxx = ws[OFF_SXF + ((b * 2 + 0) * 2 + 1) * 256 + c]
                  + ws[OFF_SXF + ((b * 2 + 1) * 2 + 1) * 256 + c];

        float sl2[16];
        float mx = -1e30f;
        #pragma unroll
        for (int k = 0; k < 16; ++k) {
            float cr = 0.f;
            #pragma unroll
            for (int sg = 0; sg < 4; ++sg)
                cr += ws[OFF_CROSSR + ((sg * 4 + b) * 16 + k) * 256 + c];
            float sc  = ws[OFF_FIN + b * 64 + 32 + k] * (1.f / 4096.f);
            float srr = ws[OFF_FIN + b * 64 + 16 + k];
            float v = sc * (sxx - 2.f * cr + srr);
            sl2[k] = v;
            mx = fmaxf(mx, v);
        }
        float den = 0.f;
        #pragma unroll
        for (int k = 0; k < 16; ++k) {
            float e = __expf(sl2[k] - mx);
            sl2[k] = e;
            den += e;
        }
        float inv = 1.f / den;
        #pragma unroll
        for (int k = 0; k < 16; ++k) {
            float srk = ws[OFF_FIN + b * 64 + k];
            out[(size_t)(b * 16 + k) * 256 + c] = sl2[k] * inv * (sx - srk);
        }
    }
}

extern "C" void kernel_launch(void* const* d_in, const int* in_sizes, int n_in,
                              void* d_out, int out_size, void* d_ws, size_t ws_size,
                              hipStream_t stream) {
    const float* x     = (const float*)d_in[0];
    const float* w     = (const float*)d_in[1];
    const float* gamma = (const float*)d_in[2];
    const float* beta  = (const float*)d_in[3];
    float* ws  = (float*)d_ws;
    float* out = (float*)d_out;

    // Residency/capacity argument (deadlock-free spin barrier):
    //   LDS 49.8 KB -> >=3 blocks/CU by LDS; 256 thr -> 8/CU; VGPR<=128 -> 4/CU.
    //   Worst-case capacity >= 2/CU x 256 CU = 512 >= grid(512): all co-resident.
    hipMemsetAsync(ws + OFF_BAR, 0, 16, stream);
    k_all<<<512, 256, 0, stream>>>(x, w, gamma, beta, ws, out);
}

// Round 10
// 108.319 us; speedup vs baseline: 2.4711x; 2.4711x over previous
//
#include <hip/hip_runtime.h>

#define BN_EPS 1e-5f

// ws layout (floats) — every region fully written each launch; no atomics,
// no memset needed: fully deterministic across replays.
#define OFF_PBN     0          // [512 blk][32]  conv BN partials (sum k<16, sq 16+k)
#define OFF_PSR     16384      // [512 blk][32]  SR/SRR partials
#define OFF_PSX     32768      // [512 blk][256] SX partials
#define OFF_PSXX    163840     // [512 blk][256] SXX partials
#define OFF_CROSSR  294912     // [4 sg][4 b][16 k][256 c]
#define OFF_CW      360448     // [b][k][4096] = 262144
#define OFF_PCX     622592     // [(b*128+s)][16][256] = 2097152
#define WS_NEED     ((size_t)(OFF_PCX + 2097152) * sizeof(float))

#define FMA16(v, rp)                                     \
    {                                                    \
        const float4* rq_ = (const float4*)(rp);         \
        float4 r0_ = rq_[0], r1_ = rq_[1];               \
        float4 r2_ = rq_[2], r3_ = rq_[3];               \
        acc[0]  = fmaf(v, r0_.x, acc[0]);                \
        acc[1]  = fmaf(v, r0_.y, acc[1]);                \
        acc[2]  = fmaf(v, r0_.z, acc[2]);                \
        acc[3]  = fmaf(v, r0_.w, acc[3]);                \
        acc[4]  = fmaf(v, r1_.x, acc[4]);                \
        acc[5]  = fmaf(v, r1_.y, acc[5]);                \
        acc[6]  = fmaf(v, r1_.z, acc[6]);                \
        acc[7]  = fmaf(v, r1_.w, acc[7]);                \
        acc[8]  = fmaf(v, r2_.x, acc[8]);                \
        acc[9]  = fmaf(v, r2_.y, acc[9]);                \
        acc[10] = fmaf(v, r2_.z, acc[10]);               \
        acc[11] = fmaf(v, r2_.w, acc[11]);               \
        acc[12] = fmaf(v, r3_.x, acc[12]);               \
        acc[13] = fmaf(v, r3_.y, acc[13]);               \
        acc[14] = fmaf(v, r3_.z, acc[14]);               \
        acc[15] = fmaf(v, r3_.w, acc[15]);               \
    }

// ---------------- Kernel 1: 1x1 conv via LDS-staged x (coalesced) ----------------
// grid 512 = 4(b) x 128(slab of 32 i); block 256.
// Stage xl[c][i] (stride 40), then GEMM from LDS: thread = (k=t&15, q=t>>4),
// q -> iq = q&7 (i-quad), h = q>>3 (c-half of 128). Lanes-along-i global reads.
__global__ __launch_bounds__(256, 2) void k_conv(const float* __restrict__ x,
                                                 const float* __restrict__ wq,
                                                 float* __restrict__ cw,
                                                 float* __restrict__ pbn) {
    __shared__ float xl[10240];      // xl[c*40 + i]; stride 40: 2-way write banks,
                                     // 16B-aligned quads for b128 compute reads
    __shared__ float wlT[4124];      // wlT[c*16 + (c>>5)*4 + k]
    __shared__ float comb[512];      // h=1 partial handoff
    __shared__ float bnr1[128], bnr2[128];
    int bid = blockIdx.x;
    int b   = bid >> 7;
    int s   = bid & 127;             // i range [s*32, s*32+32)
    int t   = threadIdx.x;
    int k   = t & 15;
    int q   = t >> 4;                // 0..15
    int iq  = q & 7;
    int h   = q >> 3;

    for (int m = t; m < 4096; m += 256) {
        int kk = m >> 8, c = m & 255;
        wlT[(c << 4) + ((c >> 5) << 2) + kk] = wq[m];
    }
    // stage x slab: 2048 float4s, lanes along i (coalesced 128B per channel row)
    #pragma unroll
    for (int j = 0; j < 8; ++j) {
        int F  = j * 256 + t;
        int cc = F >> 3, i4 = F & 7;
        float4 v = *(const float4*)(x + (size_t)(b * 256 + cc) * 4096
                                    + s * 32 + i4 * 4);
        xl[cc * 40 + i4 * 4 + 0] = v.x;
        xl[cc * 40 + i4 * 4 + 1] = v.y;
        xl[cc * 40 + i4 * 4 + 2] = v.z;
        xl[cc * 40 + i4 * 4 + 3] = v.w;
    }
    __syncthreads();

    // GEMM: acc[e] = sum_c w[k][c] * x[c][iq*4+e], over this thread's c-half
    float a0 = 0.f, a1 = 0.f, a2 = 0.f, a3 = 0.f;
    int c0 = h * 128;
    #pragma unroll 8
    for (int cc = 0; cc < 128; ++cc) {
        int c = c0 + cc;
        float4 xv = *(const float4*)&xl[c * 40 + iq * 4];
        float wv  = wlT[(c << 4) + ((c >> 5) << 2) + k];
        a0 = fmaf(wv, xv.x, a0);
        a1 = fmaf(wv, xv.y, a1);
        a2 = fmaf(wv, xv.z, a2);
        a3 = fmaf(wv, xv.w, a3);
    }
    if (h == 1) {
        int p = t & 127;
        comb[p * 4 + 0] = a0; comb[p * 4 + 1] = a1;
        comb[p * 4 + 2] = a2; comb[p * 4 + 3] = a3;
    }
    __syncthreads();
    if (h == 0) {
        a0 += comb[t * 4 + 0]; a1 += comb[t * 4 + 1];
        a2 += comb[t * 4 + 2]; a3 += comb[t * 4 + 3];
        float4 o; o.x = a0; o.y = a1; o.z = a2; o.w = a3;
        *(float4*)(cw + (size_t)b * 65536 + (size_t)k * 4096 + s * 32 + iq * 4) = o;
        bnr1[iq * 16 + k] = a0 + a1 + a2 + a3;
        bnr2[iq * 16 + k] = a0 * a0 + a1 * a1 + a2 * a2 + a3 * a3;
    }
    __syncthreads();
    if (t < 16) {
        float s1 = 0.f, s2 = 0.f;
        #pragma unroll
        for (int j = 0; j < 8; ++j) { s1 += bnr1[j * 16 + t]; s2 += bnr2[j * 16 + t]; }
        pbn[bid * 32 + t]      = s1;
        pbn[bid * 32 + 16 + t] = s2;
    }
}

// ---------------- Kernel 2: BN apply + partials for Sr/Srr/Sx/Sxx + Cross ----------
// grid 512 = 4(b) x 128(slab of 32 i); block 256 (t = channel c). Verbatim round-6
// phase B (PBN reduce bound updated to 512 rows).
__global__ __launch_bounds__(256, 2) void k_main(const float* __restrict__ x,
                                                 const float* __restrict__ gamma,
                                                 const float* __restrict__ beta,
                                                 float* __restrict__ ws,
                                                 float* __restrict__ pcx) {
    __shared__ float xl[8192];       // xl[i*256 + (c^i)] : XOR swizzle
    __shared__ float rl[512];
    __shared__ float red1[256], red2[256];
    __shared__ float bnred[256];     // [row0<8][col<32]
    int bid = blockIdx.x;
    int b   = bid >> 7;
    int s   = bid & 127;
    int kp  = s >> 3;                // flat slab of 512 sits inside one orig channel
    int t   = threadIdx.x;

    // BN stats: deterministic reduce of k_conv's 512x32 partials
    {
        int col = t & 31, row0 = t >> 5;
        float p = 0.f;
        for (int m = row0; m < 512; m += 8) p += ws[OFF_PBN + m * 32 + col];
        bnred[t] = p;
    }
    __syncthreads();
    float s1 = 0.f, s2 = 0.f;
    #pragma unroll
    for (int j = 0; j < 8; ++j) {
        s1 += bnred[j * 32 + kp];
        s2 += bnred[j * 32 + 16 + kp];
    }
    float mean = s1 * (1.f / 16384.f);
    float var  = s2 * (1.f / 16384.f) - mean * mean;
    float aa   = gamma[kp] * rsqrtf(var + BN_EPS);
    float bb   = beta[kp] - mean * aa;

    // stage x slab (256 c x 32 i): coalesced float4 reads, swizzled LDS writes
    #pragma unroll
    for (int j = 0; j < 8; ++j) {
        int F  = j * 256 + t;
        int cc = F >> 3, i4 = F & 7;
        const float* pa = x + (size_t)(b * 256 + cc) * 4096 + s * 32 + i4 * 4;
        float4 v = *(const float4*)pa;
        int ib = i4 * 4;
        xl[(ib + 0) * 256 + (cc ^ (ib + 0))] = v.x;
        xl[(ib + 1) * 256 + (cc ^ (ib + 1))] = v.y;
        xl[(ib + 2) * 256 + (cc ^ (ib + 2))] = v.z;
        xl[(ib + 3) * 256 + (cc ^ (ib + 3))] = v.w;
    }

    // r values: BN+ReLU of this slab's 512 flat cw entries; k2 = flat & 15
    const float* cwp = ws + OFF_CW + (size_t)b * 65536 + (size_t)kp * 4096
                     + (size_t)(s & 7) * 512;
    float sr = 0.f, srr = 0.f;
    #pragma unroll
    for (int j = 0; j < 2; ++j) {
        float v = cwp[t + j * 256];
        v = fmaxf(fmaf(v, aa, bb), 0.f);
        rl[t + j * 256] = v;
        sr += v; srr += v * v;
    }
    red1[t] = sr; red2[t] = srr;
    __syncthreads();

    if (t < 16) {
        float a1 = 0.f, a2 = 0.f;
        for (int m = t; m < 256; m += 16) { a1 += red1[m]; a2 += red2[m]; }
        ws[OFF_PSR + bid * 32 + t]      = a1;
        ws[OFF_PSR + bid * 32 + 16 + t] = a2;
    }

    // Cross partial: thread = channel c; 32 i from swizzled LDS; rl broadcast
    int c = t;
    float acc[16];
    #pragma unroll
    for (int k = 0; k < 16; ++k) acc[k] = 0.f;
    float xs = 0.f, xs2 = 0.f;
    #pragma unroll
    for (int ii = 0; ii < 32; ++ii) {
        float xv = xl[ii * 256 + (c ^ ii)];
        xs += xv; xs2 += xv * xv;
        FMA16(xv, rl + ii * 16);
    }

    ws[OFF_PSX  + bid * 256 + c] = xs;
    ws[OFF_PSXX + bid * 256 + c] = xs2;
    float* pp = pcx + (size_t)(bid * 16) * 256 + c;
    #pragma unroll
    for (int k = 0; k < 16; ++k) pp[(size_t)k * 256] = acc[k];
}

// ---------------- Kernel 3: reduce Cross partials (single writer) ----------------
// grid 256 = 4(b) x 16(k) x 4(sg of 32 slabs); block 256 (t = c).
__global__ __launch_bounds__(256) void k_red(const float* __restrict__ pcx,
                                             float* __restrict__ crossr) {
    int bid = blockIdx.x;
    int b  = bid >> 6;
    int k  = (bid >> 2) & 15;
    int sg = bid & 3;
    int c  = threadIdx.x;
    float acc = 0.f;
    #pragma unroll 8
    for (int m = 0; m < 32; ++m) {
        int sl = sg * 32 + m;
        acc += pcx[(size_t)((b * 128 + sl) * 16 + k) * 256 + c];
    }
    crossr[((sg * 4 + b) * 16 + k) * 256 + c] = acc;
}

// ---------------- Kernel 4: final reductions + softmax + output ----------------
// grid 4 (b), block 256 (t = c). Derives SR/SRR/SCALE from psr partials.
__global__ __launch_bounds__(256) void k_final(const float* __restrict__ ws,
                                               float* __restrict__ out) {
    __shared__ float srl[4096];    // [s<128][32]
    __shared__ float fin[48];      // SR[16], SRR[16], SCALE[16]
    int b = blockIdx.x;
    int t = threadIdx.x;

    const float* psr = ws + OFF_PSR + (size_t)b * 128 * 32;
    #pragma unroll
    for (int j = 0; j < 16; ++j) srl[j * 256 + t] = psr[j * 256 + t];
    __syncthreads();

    if (t < 16) {
        float v = 0.f;
        for (int s = 0; s < 128; ++s) v += srl[s * 32 + t];
        fin[t] = v;                                   // SR[k2]
    } else if (t < 32) {
        int k = t - 16;
        float v = 0.f;
        for (int s = 0; s < 128; ++s) v += srl[s * 32 + 16 + k];
        fin[16 + k] = v;                              // SRR[k2]
    } else if (t < 48) {
        int kp = t - 32;
        float v = 0.f;
        for (int s = kp * 8; s < kp * 8 + 8; ++s)
            for (int k2 = 0; k2 < 16; ++k2) v += srl[s * 32 + k2];
        fin[32 + kp] = v;                             // SCALE[kp] (pre /4096)
    }
    __syncthreads();

    int c = t;
    float sx = 0.f, sxx = 0.f;
    const float* psx  = ws + OFF_PSX  + (size_t)b * 128 * 256;
    const float* psxx = ws + OFF_PSXX + (size_t)b * 128 * 256;
    for (int p = 0; p < 128; ++p) {
        sx  += psx[p * 256 + c];
        sxx += psxx[p * 256 + c];
    }

    float sl2[16];
    float mx = -1e30f;
    #pragma unroll
    for (int k = 0; k < 16; ++k) {
        float cr = 0.f;
        #pragma unroll
        for (int sg = 0; sg < 4; ++sg)
            cr += ws[OFF_CROSSR + ((sg * 4 + b) * 16 + k) * 256 + c];
        float v = fin[32 + k] * (1.f / 4096.f) * (sxx - 2.f * cr + fin[16 + k]);
        sl2[k] = v;
        mx = fmaxf(mx, v);
    }
    float den = 0.f;
    #pragma unroll
    for (int k = 0; k < 16; ++k) {
        float e = __expf(sl2[k] - mx);
        sl2[k] = e;
        den += e;
    }
    float inv = 1.f / den;
    #pragma unroll
    for (int k = 0; k < 16; ++k)
        out[(size_t)(b * 16 + k) * 256 + c] = sl2[k] * inv * (sx - fin[k]);
}

extern "C" void kernel_launch(void* const* d_in, const int* in_sizes, int n_in,
                              void* d_out, int out_size, void* d_ws, size_t ws_size,
                              hipStream_t stream) {
    const float* x     = (const float*)d_in[0];
    const float* w     = (const float*)d_in[1];
    const float* gamma = (const float*)d_in[2];
    const float* beta  = (const float*)d_in[3];
    float* ws  = (float*)d_ws;
    float* out = (float*)d_out;

    k_conv<<<512, 256, 0, stream>>>(x, w, ws + OFF_CW, ws + OFF_PBN);
    k_main<<<512, 256, 0, stream>>>(x, gamma, beta, ws, ws + OFF_PCX);
    k_red<<<256, 256, 0, stream>>>(ws + OFF_PCX, ws + OFF_CROSSR);
    k_final<<<4, 256, 0, stream>>>(ws, out);
}

// Round 11
// 89.420 us; speedup vs baseline: 2.9934x; 1.2114x over previous
//
#include <hip/hip_runtime.h>

#define BN_EPS 1e-5f

// ws layout (floats) — every region fully written each launch; no atomics,
// no memset needed: fully deterministic across replays.
#define OFF_PBN     0          // [512 blk][32]  conv BN partials (sum k<16, sq 16+k)
#define OFF_PSR     16384      // [512 blk][32]  SR/SRR partials
#define OFF_PSX     32768      // [512 blk][256] SX partials
#define OFF_PSXX    163840     // [512 blk][256] SXX partials
#define OFF_CROSSR  294912     // [4 sg][4 b][16 k][256 c] = 65536
#define OFF_SXF     360448     // [4 b][4 sg][2 {sx,sxx}][256 c] = 8192
#define OFF_FIN     368640     // [4 b][64]  (SR[16], SRR[16], SCALE[16], pad)
#define OFF_CW      368896     // [b][k][4096] = 262144
#define OFF_PCX     631040     // [(b*128+s)][16][256] = 2097152

#define FMA16(v, rp)                                     \
    {                                                    \
        const float4* rq_ = (const float4*)(rp);         \
        float4 r0_ = rq_[0], r1_ = rq_[1];               \
        float4 r2_ = rq_[2], r3_ = rq_[3];               \
        acc[0]  = fmaf(v, r0_.x, acc[0]);                \
        acc[1]  = fmaf(v, r0_.y, acc[1]);                \
        acc[2]  = fmaf(v, r0_.z, acc[2]);                \
        acc[3]  = fmaf(v, r0_.w, acc[3]);                \
        acc[4]  = fmaf(v, r1_.x, acc[4]);                \
        acc[5]  = fmaf(v, r1_.y, acc[5]);                \
        acc[6]  = fmaf(v, r1_.z, acc[6]);                \
        acc[7]  = fmaf(v, r1_.w, acc[7]);                \
        acc[8]  = fmaf(v, r2_.x, acc[8]);                \
        acc[9]  = fmaf(v, r2_.y, acc[9]);                \
        acc[10] = fmaf(v, r2_.z, acc[10]);               \
        acc[11] = fmaf(v, r2_.w, acc[11]);               \
        acc[12] = fmaf(v, r3_.x, acc[12]);               \
        acc[13] = fmaf(v, r3_.y, acc[13]);               \
        acc[14] = fmaf(v, r3_.z, acc[14]);               \
        acc[15] = fmaf(v, r3_.w, acc[15]);               \
    }

// ---------------- Kernel 1: 1x1 conv via LDS-staged x (coalesced) ----------------
// grid 512 = 4(b) x 128(slab of 32 i); block 256. (unchanged from round 10)
__global__ __launch_bounds__(256, 2) void k_conv(const float* __restrict__ x,
                                                 const float* __restrict__ wq,
                                                 float* __restrict__ cw,
                                                 float* __restrict__ pbn) {
    __shared__ float xl[10240];      // xl[c*40 + i]; stride 40
    __shared__ float wlT[4124];      // wlT[c*16 + (c>>5)*4 + k]
    __shared__ float comb[512];
    __shared__ float bnr1[128], bnr2[128];
    int bid = blockIdx.x;
    int b   = bid >> 7;
    int s   = bid & 127;
    int t   = threadIdx.x;
    int k   = t & 15;
    int q   = t >> 4;
    int iq  = q & 7;
    int h   = q >> 3;

    for (int m = t; m < 4096; m += 256) {
        int kk = m >> 8, c = m & 255;
        wlT[(c << 4) + ((c >> 5) << 2) + kk] = wq[m];
    }
    #pragma unroll
    for (int j = 0; j < 8; ++j) {
        int F  = j * 256 + t;
        int cc = F >> 3, i4 = F & 7;
        float4 v = *(const float4*)(x + (size_t)(b * 256 + cc) * 4096
                                    + s * 32 + i4 * 4);
        xl[cc * 40 + i4 * 4 + 0] = v.x;
        xl[cc * 40 + i4 * 4 + 1] = v.y;
        xl[cc * 40 + i4 * 4 + 2] = v.z;
        xl[cc * 40 + i4 * 4 + 3] = v.w;
    }
    __syncthreads();

    float a0 = 0.f, a1 = 0.f, a2 = 0.f, a3 = 0.f;
    int c0 = h * 128;
    #pragma unroll 8
    for (int cc = 0; cc < 128; ++cc) {
        int c = c0 + cc;
        float4 xv = *(const float4*)&xl[c * 40 + iq * 4];
        float wv  = wlT[(c << 4) + ((c >> 5) << 2) + k];
        a0 = fmaf(wv, xv.x, a0);
        a1 = fmaf(wv, xv.y, a1);
        a2 = fmaf(wv, xv.z, a2);
        a3 = fmaf(wv, xv.w, a3);
    }
    if (h == 1) {
        int p = t & 127;
        comb[p * 4 + 0] = a0; comb[p * 4 + 1] = a1;
        comb[p * 4 + 2] = a2; comb[p * 4 + 3] = a3;
    }
    __syncthreads();
    if (h == 0) {
        a0 += comb[t * 4 + 0]; a1 += comb[t * 4 + 1];
        a2 += comb[t * 4 + 2]; a3 += comb[t * 4 + 3];
        float4 o; o.x = a0; o.y = a1; o.z = a2; o.w = a3;
        *(float4*)(cw + (size_t)b * 65536 + (size_t)k * 4096 + s * 32 + iq * 4) = o;
        bnr1[iq * 16 + k] = a0 + a1 + a2 + a3;
        bnr2[iq * 16 + k] = a0 * a0 + a1 * a1 + a2 * a2 + a3 * a3;
    }
    __syncthreads();
    if (t < 16) {
        float s1 = 0.f, s2 = 0.f;
        #pragma unroll
        for (int j = 0; j < 8; ++j) { s1 += bnr1[j * 16 + t]; s2 += bnr2[j * 16 + t]; }
        pbn[bid * 32 + t]      = s1;
        pbn[bid * 32 + 16 + t] = s2;
    }
}

// ---------------- Kernel 2: BN apply + partials for Sr/Srr/Sx/Sxx + Cross ----------
// grid 512 = 4(b) x 128(slab of 32 i); block 256 (t = channel c). (round-10 + unroll)
__global__ __launch_bounds__(256, 2) void k_main(const float* __restrict__ x,
                                                 const float* __restrict__ gamma,
                                                 const float* __restrict__ beta,
                                                 float* __restrict__ ws,
                                                 float* __restrict__ pcx) {
    __shared__ float xl[8192];       // xl[i*256 + (c^i)] : XOR swizzle
    __shared__ float rl[512];
    __shared__ float red1[256], red2[256];
    __shared__ float bnred[256];     // [row0<8][col<32]
    int bid = blockIdx.x;
    int b   = bid >> 7;
    int s   = bid & 127;
    int kp  = s >> 3;
    int t   = threadIdx.x;

    // BN stats: deterministic reduce of k_conv's 512x32 partials
    {
        int col = t & 31, row0 = t >> 5;
        float p = 0.f;
        #pragma unroll 16
        for (int m = row0; m < 512; m += 8) p += ws[OFF_PBN + m * 32 + col];
        bnred[t] = p;
    }
    __syncthreads();
    float s1 = 0.f, s2 = 0.f;
    #pragma unroll
    for (int j = 0; j < 8; ++j) {
        s1 += bnred[j * 32 + kp];
        s2 += bnred[j * 32 + 16 + kp];
    }
    float mean = s1 * (1.f / 16384.f);
    float var  = s2 * (1.f / 16384.f) - mean * mean;
    float aa   = gamma[kp] * rsqrtf(var + BN_EPS);
    float bb   = beta[kp] - mean * aa;

    // stage x slab (256 c x 32 i): coalesced float4 reads, swizzled LDS writes
    #pragma unroll
    for (int j = 0; j < 8; ++j) {
        int F  = j * 256 + t;
        int cc = F >> 3, i4 = F & 7;
        const float* pa = x + (size_t)(b * 256 + cc) * 4096 + s * 32 + i4 * 4;
        float4 v = *(const float4*)pa;
        int ib = i4 * 4;
        xl[(ib + 0) * 256 + (cc ^ (ib + 0))] = v.x;
        xl[(ib + 1) * 256 + (cc ^ (ib + 1))] = v.y;
        xl[(ib + 2) * 256 + (cc ^ (ib + 2))] = v.z;
        xl[(ib + 3) * 256 + (cc ^ (ib + 3))] = v.w;
    }

    // r values: BN+ReLU of this slab's 512 flat cw entries; k2 = flat & 15
    const float* cwp = ws + OFF_CW + (size_t)b * 65536 + (size_t)kp * 4096
                     + (size_t)(s & 7) * 512;
    float sr = 0.f, srr = 0.f;
    #pragma unroll
    for (int j = 0; j < 2; ++j) {
        float v = cwp[t + j * 256];
        v = fmaxf(fmaf(v, aa, bb), 0.f);
        rl[t + j * 256] = v;
        sr += v; srr += v * v;
    }
    red1[t] = sr; red2[t] = srr;
    __syncthreads();

    if (t < 16) {
        float a1 = 0.f, a2 = 0.f;
        #pragma unroll
        for (int m = t; m < 256; m += 16) { a1 += red1[m]; a2 += red2[m]; }
        ws[OFF_PSR + bid * 32 + t]      = a1;
        ws[OFF_PSR + bid * 32 + 16 + t] = a2;
    }

    // Cross partial: thread = channel c; 32 i from swizzled LDS; rl broadcast
    int c = t;
    float acc[16];
    #pragma unroll
    for (int k = 0; k < 16; ++k) acc[k] = 0.f;
    float xs = 0.f, xs2 = 0.f;
    #pragma unroll
    for (int ii = 0; ii < 32; ++ii) {
        float xv = xl[ii * 256 + (c ^ ii)];
        xs += xv; xs2 += xv * xv;
        FMA16(xv, rl + ii * 16);
    }

    ws[OFF_PSX  + bid * 256 + c] = xs;
    ws[OFF_PSXX + bid * 256 + c] = xs2;
    float* pp = pcx + (size_t)(bid * 16) * 256 + c;
    #pragma unroll
    for (int k = 0; k < 16; ++k) pp[(size_t)k * 256] = acc[k];
}

// ---------------- Kernel 3: ALL wide reductions (cross, sx/sxx, sr/srr/scale) -----
// grid 260; block 256. Blocks 0-255: (b,k,sg) cross-reduce 32 slabs + SXF chunks.
// Blocks 256-259: per-b PSR -> FIN (all 256 threads parallel).
__global__ __launch_bounds__(256) void k_red(const float* __restrict__ pcx,
                                             float* __restrict__ ws) {
    __shared__ float pred[16][32];
    int bid = blockIdx.x;
    int t   = threadIdx.x;

    if (bid < 256) {
        int b  = bid >> 6;
        int k  = (bid >> 2) & 15;
        int sg = bid & 3;
        int c  = t;
        float acc = 0.f;
        #pragma unroll
        for (int m = 0; m < 32; ++m)
            acc += pcx[(size_t)((b * 128 + sg * 32 + m) * 16 + k) * 256 + c];
        ws[OFF_CROSSR + ((sg * 4 + b) * 16 + k) * 256 + c] = acc;

        if (k == 0) {
            float sv = 0.f;
            #pragma unroll
            for (int m = 0; m < 32; ++m)
                sv += ws[OFF_PSX + (size_t)(b * 128 + sg * 32 + m) * 256 + c];
            ws[OFF_SXF + ((b * 4 + sg) * 2 + 0) * 256 + c] = sv;
        } else if (k == 1) {
            float sv = 0.f;
            #pragma unroll
            for (int m = 0; m < 32; ++m)
                sv += ws[OFF_PSXX + (size_t)(b * 128 + sg * 32 + m) * 256 + c];
            ws[OFF_SXF + ((b * 4 + sg) * 2 + 1) * 256 + c] = sv;
        }
    } else {
        int b   = bid - 256;
        int col = t & 31, ch = t >> 5;   // ch 0..7, each covers 16 rows = 2 channels
        const float* psr = ws + OFF_PSR + (size_t)b * 128 * 32;
        float p0 = 0.f, p1 = 0.f;
        #pragma unroll
        for (int j = 0; j < 8; ++j) p0 += psr[(ch * 16 + j) * 32 + col];
        #pragma unroll
        for (int j = 0; j < 8; ++j) p1 += psr[(ch * 16 + 8 + j) * 32 + col];
        pred[ch * 2][col]     = p0;      // chunk q = channel q's 8 slabs
        pred[ch * 2 + 1][col] = p1;
        __syncthreads();
        if (t < 16) {
            float v = 0.f;
            #pragma unroll
            for (int q2 = 0; q2 < 16; ++q2) v += pred[q2][t];
            ws[OFF_FIN + b * 64 + t] = v;               // SR[k2]
        } else if (t < 32) {
            int k = t - 16;
            float v = 0.f;
            #pragma unroll
            for (int q2 = 0; q2 < 16; ++q2) v += pred[q2][16 + k];
            ws[OFF_FIN + b * 64 + 16 + k] = v;          // SRR[k2]
        } else if (t < 48) {
            int kp = t - 32;
            float v = 0.f;
            #pragma unroll
            for (int k2 = 0; k2 < 16; ++k2) v += pred[kp][k2];
            ws[OFF_FIN + b * 64 + 32 + kp] = v;         // SCALE[kp] (pre /4096)
        }
    }
}

// ---------------- Kernel 4: softmax + output (cheap now) ----------------
// grid 4 (b), block 256 (t = c): 8 SXF + 64 CROSSR + 48 FIN loads, all independent.
__global__ __launch_bounds__(256) void k_final(const float* __restrict__ ws,
                                               float* __restrict__ out) {
    int b = blockIdx.x;
    int c = threadIdx.x;
    float sx = 0.f, sxx = 0.f;
    #pragma unroll
    for (int sg = 0; sg < 4; ++sg) {
        sx  += ws[OFF_SXF + ((b * 4 + sg) * 2 + 0) * 256 + c];
        sxx += ws[OFF_SXF + ((b * 4 + sg) * 2 + 1) * 256 + c];
    }

    float sl2[16];
    float mx = -1e30f;
    #pragma unroll
    for (int k = 0; k < 16; ++k) {
        float cr = 0.f;
        #pragma unroll
        for (int sg = 0; sg < 4; ++sg)
            cr += ws[OFF_CROSSR + ((sg * 4 + b) * 16 + k) * 256 + c];
        float v = ws[OFF_FIN + b * 64 + 32 + k] * (1.f / 4096.f)
                * (sxx - 2.f * cr + ws[OFF_FIN + b * 64 + 16 + k]);
        sl2[k] = v;
        mx = fmaxf(mx, v);
    }
    float den = 0.f;
    #pragma unroll
    for (int k = 0; k < 16; ++k) {
        float e = __expf(sl2[k] - mx);
        sl2[k] = e;
        den += e;
    }
    float inv = 1.f / den;
    #pragma unroll
    for (int k = 0; k < 16; ++k)
        out[(size_t)(b * 16 + k) * 256 + c]
            = sl2[k] * inv * (sx - ws[OFF_FIN + b * 64 + k]);
}

extern "C" void kernel_launch(void* const* d_in, const int* in_sizes, int n_in,
                              void* d_out, int out_size, void* d_ws, size_t ws_size,
                              hipStream_t stream) {
    const float* x     = (const float*)d_in[0];
    const float* w     = (const float*)d_in[1];
    const float* gamma = (const float*)d_in[2];
    const float* beta  = (const float*)d_in[3];
    float* ws  = (float*)d_ws;
    float* out = (float*)d_out;

    k_conv<<<512, 256, 0, stream>>>(x, w, ws + OFF_CW, ws + OFF_PBN);
    k_main<<<512, 256, 0, stream>>>(x, gamma, beta, ws, ws + OFF_PCX);
    k_red<<<260, 256, 0, stream>>>(ws + OFF_PCX, ws);
    k_final<<<4, 256, 0, stream>>>(ws, out);
}